// Round 2
// baseline (414.542 us; speedup 1.0000x reference)
//
#include <hip/hip_runtime.h>

#define N_NODES 50000
#define N_EDGES 800000
#define M_IDX   25000
#define ADJ_STRIDE 64   // max degree safety: Poisson(16), P(deg>=64) ~ 1e-18

// ---------------------------------------------------------------------------
// Build padded CSR-by-dst: adj[t*ADJ_STRIDE + p] = src. No scan needed.
// ---------------------------------------------------------------------------
__global__ __launch_bounds__(256) void build_adj_kernel(
    const int* __restrict__ src, const int* __restrict__ dst,
    int* __restrict__ cnt, int* __restrict__ adj, int E)
{
    int e = blockIdx.x * blockDim.x + threadIdx.x;
    if (e >= E) return;
    int t = dst[e];
    int p = atomicAdd(&cnt[t], 1);
    if (p < ADJ_STRIDE) adj[t * ADJ_STRIDE + p] = src[e];
}

// ---------------------------------------------------------------------------
// Fused per-layer kernel: 16 lanes per node, lane o = output channel o.
// Gathers incident edges from CSR, accumulates msg in registers, then
// mean + root GEMV + bias + ReLU, coalesced write. Folded edge-MLP weights
// (lin_w*gamma, lin_b*gamma+beta) in registers; next-edge data prefetched.
// ---------------------------------------------------------------------------
template<int CI>
__global__ __launch_bounds__(256) void aggr_node_kernel(
    const float* __restrict__ pos,     // [N,3]
    const int*   __restrict__ adj,     // [N,ADJ_STRIDE]
    const int*   __restrict__ cnt,     // [N]
    const float* __restrict__ h_in,    // [N,CI]
    const float* __restrict__ lin_w,   // [3, CI*16]
    const float* __restrict__ lin_b,   // [CI*16]
    const float* __restrict__ gamma,   // [CI*16]
    const float* __restrict__ beta,    // [CI*16]
    const float* __restrict__ root,    // [CI,16]
    const float* __restrict__ bias,    // [16]
    float*       __restrict__ h_out,   // [N,16]
    int nNodes)
{
    const int o = threadIdx.x & 15;
    const int d = CI * 16;
    float W0[CI], W1[CI], W2[CI], B[CI];
#pragma unroll
    for (int i = 0; i < CI; ++i) {
        int j = i * 16 + o;
        float g = gamma[j];
        W0[i] = lin_w[j] * g;
        W1[i] = lin_w[d + j] * g;
        W2[i] = lin_w[2 * d + j] * g;
        B[i]  = fmaf(lin_b[j], g, beta[j]);
    }
    const float bo = bias[o];

    const int group   = (blockIdx.x * blockDim.x + threadIdx.x) >> 4;
    const int ngroups = (gridDim.x * blockDim.x) >> 4;
    for (int t = group; t < nNodes; t += ngroups) {
        const int deg  = cnt[t];
        const int base = t * ADJ_STRIDE;
        const float pt0 = pos[t * 3 + 0];
        const float pt1 = pos[t * 3 + 1];
        const float pt2 = pos[t * 3 + 2];

        float acc = 0.f;
        // software-pipelined edge loop: prefetch next edge's pos/x
        float pn0 = 0.f, pn1 = 0.f, pn2 = 0.f;
        float xn[CI];
#pragma unroll
        for (int i = 0; i < CI; ++i) xn[i] = 0.f;
        if (deg > 0) {
            int s = adj[base];
            pn0 = pos[s * 3 + 0]; pn1 = pos[s * 3 + 1]; pn2 = pos[s * 3 + 2];
            const float4* xp = (const float4*)(h_in + (size_t)s * CI);
#pragma unroll
            for (int q = 0; q < CI / 4; ++q) {
                float4 v = xp[q];
                xn[4 * q + 0] = v.x; xn[4 * q + 1] = v.y;
                xn[4 * q + 2] = v.z; xn[4 * q + 3] = v.w;
            }
        }
        for (int p = 0; p < deg; ++p) {
            const float p0 = pt0 - pn0;
            const float p1 = pt1 - pn1;
            const float p2 = pt2 - pn2;
            float xc[CI];
#pragma unroll
            for (int i = 0; i < CI; ++i) xc[i] = xn[i];
            if (p + 1 < deg) {
                int s = adj[base + p + 1];
                pn0 = pos[s * 3 + 0]; pn1 = pos[s * 3 + 1]; pn2 = pos[s * 3 + 2];
                const float4* xp = (const float4*)(h_in + (size_t)s * CI);
#pragma unroll
                for (int q = 0; q < CI / 4; ++q) {
                    float4 v = xp[q];
                    xn[4 * q + 0] = v.x; xn[4 * q + 1] = v.y;
                    xn[4 * q + 2] = v.z; xn[4 * q + 3] = v.w;
                }
            }
#pragma unroll
            for (int i = 0; i < CI; ++i) {
                float w = fmaf(p2, W2[i], fmaf(p1, W1[i], fmaf(p0, W0[i], B[i])));
                w = fmaxf(w, 0.f);
                acc = fmaf(xc[i], w, acc);
            }
        }
        const float inv = 1.0f / fmaxf((float)deg, 1.0f);
        float r = fmaf(acc, inv, bo);
        // root term: r += h_in[t,:] @ root[:,o]   (root reloaded, L1-hot)
        const float4* hp = (const float4*)(h_in + (size_t)t * CI);
#pragma unroll
        for (int q = 0; q < CI / 4; ++q) {
            float4 v = hp[q];
            r = fmaf(v.x, root[(4 * q + 0) * 16 + o], r);
            r = fmaf(v.y, root[(4 * q + 1) * 16 + o], r);
            r = fmaf(v.z, root[(4 * q + 2) * 16 + o], r);
            r = fmaf(v.w, root[(4 * q + 3) * 16 + o], r);
        }
        h_out[(size_t)t * 16 + o] = fmaxf(r, 0.f);
    }
}

// ---------------------------------------------------------------------------
// Output gather: out = [h[idx] (M*16) | pos[idx] (M*3) | batch[idx] (M)]
// ---------------------------------------------------------------------------
__global__ __launch_bounds__(256) void gather_kernel(
    const float* __restrict__ h,
    const float* __restrict__ pos,
    const int*   __restrict__ batch,
    const int*   __restrict__ idx,
    float*       __restrict__ out,
    int M)
{
    int j = blockIdx.x * blockDim.x + threadIdx.x;
    if (j >= M) return;
    int n = idx[j];
    float4*       o4 = (float4*)out + (size_t)j * 4;
    const float4* h4 = (const float4*)(h + (size_t)n * 16);
    o4[0] = h4[0]; o4[1] = h4[1]; o4[2] = h4[2]; o4[3] = h4[3];
    float* po = out + (size_t)M * 16 + (size_t)j * 3;
    po[0] = pos[n * 3 + 0];
    po[1] = pos[n * 3 + 1];
    po[2] = pos[n * 3 + 2];
    ((int*)out)[(size_t)M * 19 + j] = batch[n];
}

extern "C" void kernel_launch(void* const* d_in, const int* in_sizes, int n_in,
                              void* d_out, int out_size, void* d_ws, size_t ws_size,
                              hipStream_t stream) {
    const float* x      = (const float*)d_in[0];
    const float* pos    = (const float*)d_in[1];
    const float* lin_w0 = (const float*)d_in[2];
    const float* lin_b0 = (const float*)d_in[3];
    const float* gamma0 = (const float*)d_in[4];
    const float* beta0  = (const float*)d_in[5];
    const float* root0  = (const float*)d_in[6];
    const float* bias0  = (const float*)d_in[7];
    const float* lin_w1 = (const float*)d_in[8];
    const float* lin_b1 = (const float*)d_in[9];
    const float* gamma1 = (const float*)d_in[10];
    const float* beta1  = (const float*)d_in[11];
    const float* root1  = (const float*)d_in[12];
    const float* bias1  = (const float*)d_in[13];
    const float* lin_w2 = (const float*)d_in[14];
    const float* lin_b2 = (const float*)d_in[15];
    const float* gamma2 = (const float*)d_in[16];
    const float* beta2  = (const float*)d_in[17];
    const float* root2  = (const float*)d_in[18];
    const float* bias2  = (const float*)d_in[19];
    const int*   batch  = (const int*)d_in[20];
    const int*   idx    = (const int*)d_in[21];
    const int*   ei     = (const int*)d_in[22];
    const int*   src    = ei;
    const int*   dst    = ei + N_EDGES;
    float*       out    = (float*)d_out;

    // workspace layout
    int*   adj = (int*)d_ws;                                   // N*ADJ_STRIDE ints (12.8 MB)
    float* hA  = (float*)(adj + (size_t)N_NODES * ADJ_STRIDE); // N*16 floats
    float* hB  = hA + (size_t)N_NODES * 16;                    // N*16 floats
    int*   cnt = (int*)(hB + (size_t)N_NODES * 16);            // N ints

    const int AGG_BLOCKS = 1024;  // 4 blocks/CU, grid-stride over nodes

    hipMemsetAsync(cnt, 0, N_NODES * sizeof(int), stream);
    build_adj_kernel<<<(N_EDGES + 255) / 256, 256, 0, stream>>>(src, dst, cnt, adj, N_EDGES);

    // ---- layer 0: ci=8 ----
    aggr_node_kernel<8><<<AGG_BLOCKS, 256, 0, stream>>>(
        pos, adj, cnt, x, lin_w0, lin_b0, gamma0, beta0, root0, bias0, hA, N_NODES);
    // ---- layer 1: ci=16 ----
    aggr_node_kernel<16><<<AGG_BLOCKS, 256, 0, stream>>>(
        pos, adj, cnt, hA, lin_w1, lin_b1, gamma1, beta1, root1, bias1, hB, N_NODES);
    // ---- layer 2: ci=16 ----
    aggr_node_kernel<16><<<AGG_BLOCKS, 256, 0, stream>>>(
        pos, adj, cnt, hB, lin_w2, lin_b2, gamma2, beta2, root2, bias2, hA, N_NODES);

    // ---- output gather ----
    gather_kernel<<<(M_IDX + 255) / 256, 256, 0, stream>>>(hA, pos, batch, idx, out, M_IDX);
}

// Round 3
// 331.688 us; speedup vs baseline: 1.2498x; 1.2498x over previous
//
#include <hip/hip_runtime.h>

#define N_NODES 50000
#define N_EDGES 800000
#define M_IDX   25000
#define DMAX    64   // Poisson(16) degree; P(deg>=64) ~ 1e-18 -- safe pad

// ---------------------------------------------------------------------------
// Prep (once): pseudo[e] = {pos[t]-pos[s], src-bits}; adjacency of edge ids
// (adj[t*DMAX+p] = e) with a single atomic per edge; cnt[t] = degree.
// ---------------------------------------------------------------------------
__global__ __launch_bounds__(256) void prep_kernel(
    const int*   __restrict__ ei,     // [2,E]
    const float* __restrict__ pos,    // [N,3]
    float4*      __restrict__ pseudo, // [E] xyz = pseudo, w = src (int bits)
    int*         __restrict__ cnt,    // [N] (pre-zeroed)
    int*         __restrict__ adj,    // [N,DMAX] edge ids
    int E)
{
    int e = blockIdx.x * blockDim.x + threadIdx.x;
    if (e >= E) return;
    int s = ei[e];
    int t = ei[E + e];
    float4 pd;
    pd.x = pos[t * 3 + 0] - pos[s * 3 + 0];
    pd.y = pos[t * 3 + 1] - pos[s * 3 + 1];
    pd.z = pos[t * 3 + 2] - pos[s * 3 + 2];
    pd.w = __int_as_float(s);
    pseudo[e] = pd;
    int p = atomicAdd(&cnt[t], 1);
    if (p < DMAX) adj[t * DMAX + p] = e;
}

// ---------------------------------------------------------------------------
// Phase A: per-edge messages, 16 lanes/edge (lane o = out channel), folded
// edge-MLP weights in registers, 2 edges in flight per thread, coalesced
// mbuf[e*16+o] writes, no atomics.
// ---------------------------------------------------------------------------
template<int CI>
__global__ __launch_bounds__(256) void edge_msg_kernel(
    const float4* __restrict__ pseudo, // [E]
    const float*  __restrict__ h_in,   // [N,CI]
    const float*  __restrict__ lin_w,  // [3, CI*16]
    const float*  __restrict__ lin_b,  // [CI*16]
    const float*  __restrict__ gamma,  // [CI*16]
    const float*  __restrict__ beta,   // [CI*16]
    float*        __restrict__ mbuf,   // [E,16]
    int E)
{
    const int o = threadIdx.x & 15;
    const int d = CI * 16;
    float W0[CI], W1[CI], W2[CI], B[CI];
#pragma unroll
    for (int i = 0; i < CI; ++i) {
        int j = i * 16 + o;
        float g = gamma[j];
        W0[i] = lin_w[j] * g;
        W1[i] = lin_w[d + j] * g;
        W2[i] = lin_w[2 * d + j] * g;
        B[i]  = fmaf(lin_b[j], g, beta[j]);
    }
    const int g   = (blockIdx.x * blockDim.x + threadIdx.x) >> 4;
    const int ng  = (gridDim.x * blockDim.x) >> 4;

    for (int e0 = g; e0 < E; e0 += 2 * ng) {
        const int e1 = e0 + ng;
        const bool v1 = (e1 < E);
        float4 pd0 = pseudo[e0];
        float4 pd1 = v1 ? pseudo[e1] : pd0;
        const int s0 = __float_as_int(pd0.w);
        const int s1 = __float_as_int(pd1.w);
        float x0[CI], x1[CI];
        const float4* xp0 = (const float4*)(h_in + (size_t)s0 * CI);
        const float4* xp1 = (const float4*)(h_in + (size_t)s1 * CI);
#pragma unroll
        for (int q = 0; q < CI / 4; ++q) {
            float4 a = xp0[q];
            x0[4 * q + 0] = a.x; x0[4 * q + 1] = a.y;
            x0[4 * q + 2] = a.z; x0[4 * q + 3] = a.w;
            float4 b = xp1[q];
            x1[4 * q + 0] = b.x; x1[4 * q + 1] = b.y;
            x1[4 * q + 2] = b.z; x1[4 * q + 3] = b.w;
        }
        float a0 = 0.f, a1 = 0.f;
#pragma unroll
        for (int i = 0; i < CI; ++i) {
            float w0 = fmaf(pd0.z, W2[i], fmaf(pd0.y, W1[i], fmaf(pd0.x, W0[i], B[i])));
            a0 = fmaf(x0[i], fmaxf(w0, 0.f), a0);
            float w1 = fmaf(pd1.z, W2[i], fmaf(pd1.y, W1[i], fmaf(pd1.x, W0[i], B[i])));
            a1 = fmaf(x1[i], fmaxf(w1, 0.f), a1);
        }
        mbuf[(size_t)e0 * 16 + o] = a0;
        if (v1) mbuf[(size_t)e1 * 16 + o] = a1;
    }
}

// ---------------------------------------------------------------------------
// Phase B: thread per (node, channel). Sum this node's edge messages via
// int4 adjacency reads (4 independent 64B gathers per round), then fuse
// mean + root GEMV + bias + ReLU.
// ---------------------------------------------------------------------------
template<int CI>
__global__ __launch_bounds__(256) void node_reduce_kernel(
    const int*   __restrict__ adj,    // [N,DMAX]
    const int*   __restrict__ cnt,    // [N]
    const float* __restrict__ mbuf,   // [E,16]
    const float* __restrict__ h_in,   // [N,CI]
    const float* __restrict__ root,   // [CI,16]
    const float* __restrict__ bias,   // [16]
    float*       __restrict__ h_out,  // [N,16]
    int N)
{
    int tid = blockIdx.x * blockDim.x + threadIdx.x;
    if (tid >= N * 16) return;
    const int t = tid >> 4, o = tid & 15;
    const int deg = cnt[t];
    const int dl  = min(deg, DMAX);
    const int4* arow = (const int4*)(adj + (size_t)t * DMAX);
    float acc = 0.f;
    const int rounds = (dl + 3) >> 2;
    for (int r = 0; r < rounds; ++r) {
        int4 e4 = arow[r];
        int base = r * 4;
        bool m0 = base + 0 < dl, m1 = base + 1 < dl;
        bool m2 = base + 2 < dl, m3 = base + 3 < dl;
        int i0 = m0 ? e4.x : 0, i1 = m1 ? e4.y : 0;
        int i2 = m2 ? e4.z : 0, i3 = m3 ? e4.w : 0;
        float v0 = mbuf[(size_t)i0 * 16 + o];
        float v1 = mbuf[(size_t)i1 * 16 + o];
        float v2 = mbuf[(size_t)i2 * 16 + o];
        float v3 = mbuf[(size_t)i3 * 16 + o];
        acc += (m0 ? v0 : 0.f) + (m1 ? v1 : 0.f) + (m2 ? v2 : 0.f) + (m3 ? v3 : 0.f);
    }
    float r = fmaf(acc, 1.0f / fmaxf((float)deg, 1.0f), bias[o]);
    const float4* hp = (const float4*)(h_in + (size_t)t * CI);
#pragma unroll
    for (int q = 0; q < CI / 4; ++q) {
        float4 v = hp[q];
        r = fmaf(v.x, root[(4 * q + 0) * 16 + o], r);
        r = fmaf(v.y, root[(4 * q + 1) * 16 + o], r);
        r = fmaf(v.z, root[(4 * q + 2) * 16 + o], r);
        r = fmaf(v.w, root[(4 * q + 3) * 16 + o], r);
    }
    h_out[tid] = fmaxf(r, 0.f);
}

// ---------------------------------------------------------------------------
// Output gather: out = [h[idx] (M*16) | pos[idx] (M*3) | batch[idx] (M)]
// ---------------------------------------------------------------------------
__global__ __launch_bounds__(256) void gather_kernel(
    const float* __restrict__ h,
    const float* __restrict__ pos,
    const int*   __restrict__ batch,
    const int*   __restrict__ idx,
    float*       __restrict__ out,
    int M)
{
    int j = blockIdx.x * blockDim.x + threadIdx.x;
    if (j >= M) return;
    int n = idx[j];
    float4*       o4 = (float4*)out + (size_t)j * 4;
    const float4* h4 = (const float4*)(h + (size_t)n * 16);
    o4[0] = h4[0]; o4[1] = h4[1]; o4[2] = h4[2]; o4[3] = h4[3];
    float* po = out + (size_t)M * 16 + (size_t)j * 3;
    po[0] = pos[n * 3 + 0];
    po[1] = pos[n * 3 + 1];
    po[2] = pos[n * 3 + 2];
    ((int*)out)[(size_t)M * 19 + j] = batch[n];
}

extern "C" void kernel_launch(void* const* d_in, const int* in_sizes, int n_in,
                              void* d_out, int out_size, void* d_ws, size_t ws_size,
                              hipStream_t stream) {
    const float* x      = (const float*)d_in[0];
    const float* pos    = (const float*)d_in[1];
    const float* lin_w0 = (const float*)d_in[2];
    const float* lin_b0 = (const float*)d_in[3];
    const float* gamma0 = (const float*)d_in[4];
    const float* beta0  = (const float*)d_in[5];
    const float* root0  = (const float*)d_in[6];
    const float* bias0  = (const float*)d_in[7];
    const float* lin_w1 = (const float*)d_in[8];
    const float* lin_b1 = (const float*)d_in[9];
    const float* gamma1 = (const float*)d_in[10];
    const float* beta1  = (const float*)d_in[11];
    const float* root1  = (const float*)d_in[12];
    const float* bias1  = (const float*)d_in[13];
    const float* lin_w2 = (const float*)d_in[14];
    const float* lin_b2 = (const float*)d_in[15];
    const float* gamma2 = (const float*)d_in[16];
    const float* beta2  = (const float*)d_in[17];
    const float* root2  = (const float*)d_in[18];
    const float* bias2  = (const float*)d_in[19];
    const int*   batch  = (const int*)d_in[20];
    const int*   idx    = (const int*)d_in[21];
    const int*   ei     = (const int*)d_in[22];
    float*       out    = (float*)d_out;

    // workspace layout (all 16B aligned)
    float4* pseudo = (float4*)d_ws;                              // E float4 (12.8 MB)
    float*  mbuf   = (float*)(pseudo + N_EDGES);                 // E*16 floats (51.2 MB)
    int*    adj    = (int*)(mbuf + (size_t)N_EDGES * 16);        // N*DMAX ints (12.8 MB)
    float*  hA     = (float*)(adj + (size_t)N_NODES * DMAX);     // N*16 floats
    float*  hB     = hA + (size_t)N_NODES * 16;                  // N*16 floats
    int*    cnt    = (int*)(hB + (size_t)N_NODES * 16);          // N ints

    const int EB = 2048;                       // phase-A blocks (grid-stride)
    const int NB = (N_NODES * 16 + 255) / 256; // phase-B blocks

    hipMemsetAsync(cnt, 0, N_NODES * sizeof(int), stream);
    prep_kernel<<<(N_EDGES + 255) / 256, 256, 0, stream>>>(ei, pos, pseudo, cnt, adj, N_EDGES);

    // ---- layer 0: ci=8 ----
    edge_msg_kernel<8><<<EB, 256, 0, stream>>>(pseudo, x, lin_w0, lin_b0, gamma0, beta0, mbuf, N_EDGES);
    node_reduce_kernel<8><<<NB, 256, 0, stream>>>(adj, cnt, mbuf, x, root0, bias0, hA, N_NODES);

    // ---- layer 1: ci=16 ----
    edge_msg_kernel<16><<<EB, 256, 0, stream>>>(pseudo, hA, lin_w1, lin_b1, gamma1, beta1, mbuf, N_EDGES);
    node_reduce_kernel<16><<<NB, 256, 0, stream>>>(adj, cnt, mbuf, hA, root1, bias1, hB, N_NODES);

    // ---- layer 2: ci=16 ----
    edge_msg_kernel<16><<<EB, 256, 0, stream>>>(pseudo, hB, lin_w2, lin_b2, gamma2, beta2, mbuf, N_EDGES);
    node_reduce_kernel<16><<<NB, 256, 0, stream>>>(adj, cnt, mbuf, hB, root2, bias2, hA, N_NODES);

    // ---- output gather ----
    gather_kernel<<<(M_IDX + 255) / 256, 256, 0, stream>>>(hA, pos, batch, idx, out, M_IDX);
}